// Round 9
// baseline (637.127 us; speedup 1.0000x reference)
//
#include <hip/hip_runtime.h>
#include <hip/hip_cooperative_groups.h>

namespace cg = cooperative_groups;

typedef short short8 __attribute__((ext_vector_type(8)));
typedef float floatx4 __attribute__((ext_vector_type(4)));

__device__ __forceinline__ unsigned short f2bf(float f) {
  unsigned int u = __float_as_uint(f);
  u += 0x7FFFu + ((u >> 16) & 1u);   // RNE
  return (unsigned short)(u >> 16);
}

#if __has_builtin(__builtin_amdgcn_cvt_pk_bf16_f32)
typedef __bf16 bf16x2_t __attribute__((ext_vector_type(2)));
__device__ __forceinline__ unsigned int pk2bf(float lo, float hi) {
  bf16x2_t v = __builtin_amdgcn_cvt_pk_bf16_f32(lo, hi);
  return __builtin_bit_cast(unsigned int, v);
}
#else
__device__ __forceinline__ unsigned int pk2bf(float lo, float hi) {
  return (unsigned)f2bf(lo) | ((unsigned)f2bf(hi) << 16);
}
#endif

__device__ __forceinline__ float silu(float h) {
  return h * __builtin_amdgcn_rcpf(1.f + __expf(-h));
}

// ---------------------------------------------------------------------------
// Shared device helpers (used by both coop and fallback paths)
// wbuf (ushort): [0,16384) W1x frags [nt=8][ks=4][lane=64][j=8];
// [16384,32768) W1p; [32768,40960) W2x [nt=4][...]. val = W[k][n],
// k = ks*32+(lane>>4)*8+j, n = nt*16+(lane&15). A/B layouts coincide.
// ---------------------------------------------------------------------------
__device__ __forceinline__ void repack_item(
    int i, const float* __restrict__ W1x, const float* __restrict__ W1p,
    const float* __restrict__ W2x, unsigned short* __restrict__ wbuf) {
  int jj = i & 7, lane = (i >> 3) & 63, ks = (i >> 9) & 3;
  int k = ks*32 + (lane >> 4)*8 + jj;
  float v;
  if (i < 32768) {
    const float* W = (i < 16384) ? W1x : W1p;
    int nt = (i >> 11) & 7;
    v = W[k*128 + nt*16 + (lane & 15)];
  } else {
    int nt = (i >> 11) & 3;
    v = W2x[k*64 + nt*16 + (lane & 15)];
  }
  wbuf[i] = f2bf(v);
}

// Per-node layer-1 partials (R8-validated orientation: D[h][node], uint4 store)
//   Ar[n][h] = x[n]·W1[0:64,h] + b1[h] ; Ac[n][h] = x[n]·W1[64:128,h]
// packed per h: uint = (x_bf16 | p_bf16<<16).
struct NodeAFrags {
  short8 fxr[2][2], fxc[2][2], fpr[2][2], fpc[2][2];
  float bxv[2][4], bpv[2][4];
};

__device__ __forceinline__ void nodeA_load_frags(
    NodeAFrags& F, const unsigned short* __restrict__ wbuf,
    const float* __restrict__ b1x, const float* __restrict__ b1p,
    int wv, int lane, int quad) {
  const short8* w1x_f = (const short8*)wbuf;
  const short8* w1p_f = (const short8*)(wbuf + 16384);
  #pragma unroll
  for (int ti = 0; ti < 2; ++ti) {
    int nt = wv + 4*ti;
    #pragma unroll
    for (int k2 = 0; k2 < 2; ++k2) {
      F.fxr[ti][k2] = w1x_f[(nt*4 + k2)*64 + lane];
      F.fxc[ti][k2] = w1x_f[(nt*4 + 2 + k2)*64 + lane];
      F.fpr[ti][k2] = w1p_f[(nt*4 + k2)*64 + lane];
      F.fpc[ti][k2] = w1p_f[(nt*4 + 2 + k2)*64 + lane];
    }
    #pragma unroll
    for (int r = 0; r < 4; ++r) {
      F.bxv[ti][r] = b1x[nt*16 + quad*4 + r];
      F.bpv[ti][r] = b1p[nt*16 + quad*4 + r];
    }
  }
}

__device__ __forceinline__ void nodeA_tile(
    int n0, const float* __restrict__ x, const NodeAFrags& F, int N,
    unsigned int* __restrict__ Ar, unsigned int* __restrict__ Ac,
    unsigned short (*xt)[72], int t) {
  const int wv = t >> 6, lane = t & 63, quad = lane >> 4, lc = lane & 15;
  {  // stage x tile (bf16)
    int nd = t >> 2, p = t & 3;
    int n = n0 + nd;
    uint4 o0, o1;
    if (n < N) {
      const float4* xp = (const float4*)(x + (size_t)n*64 + p*16);
      float4 a = xp[0], b = xp[1], c = xp[2], d = xp[3];
      o0 = make_uint4(pk2bf(a.x,a.y), pk2bf(a.z,a.w), pk2bf(b.x,b.y), pk2bf(b.z,b.w));
      o1 = make_uint4(pk2bf(c.x,c.y), pk2bf(c.z,c.w), pk2bf(d.x,d.y), pk2bf(d.z,d.w));
    } else {
      o0 = o1 = make_uint4(0u,0u,0u,0u);
    }
    *(uint4*)&xt[nd][p*16]     = o0;
    *(uint4*)&xt[nd][p*16 + 8] = o1;
  }
  __syncthreads();
  #pragma unroll 1
  for (int mw = 0; mw < 4; ++mw) {
    short8 b0  = *(const short8*)&xt[mw*16 + lc][quad*8];       // k 0..31
    short8 b1f = *(const short8*)&xt[mw*16 + lc][32 + quad*8];  // k 32..63
    const int nd = n0 + mw*16 + lc;
    #pragma unroll
    for (int ti = 0; ti < 2; ++ti) {
      floatx4 xr = {0,0,0,0}, xc = {0,0,0,0}, pr = {0,0,0,0}, pc = {0,0,0,0};
      xr = __builtin_amdgcn_mfma_f32_16x16x32_bf16(F.fxr[ti][0], b0,  xr, 0,0,0);
      xr = __builtin_amdgcn_mfma_f32_16x16x32_bf16(F.fxr[ti][1], b1f, xr, 0,0,0);
      xc = __builtin_amdgcn_mfma_f32_16x16x32_bf16(F.fxc[ti][0], b0,  xc, 0,0,0);
      xc = __builtin_amdgcn_mfma_f32_16x16x32_bf16(F.fxc[ti][1], b1f, xc, 0,0,0);
      pr = __builtin_amdgcn_mfma_f32_16x16x32_bf16(F.fpr[ti][0], b0,  pr, 0,0,0);
      pr = __builtin_amdgcn_mfma_f32_16x16x32_bf16(F.fpr[ti][1], b1f, pr, 0,0,0);
      pc = __builtin_amdgcn_mfma_f32_16x16x32_bf16(F.fpc[ti][0], b0,  pc, 0,0,0);
      pc = __builtin_amdgcn_mfma_f32_16x16x32_bf16(F.fpc[ti][1], b1f, pc, 0,0,0);
      if (nd < N) {
        const int hbase = (wv + 4*ti)*16 + quad*4;
        uint4 ur = make_uint4(pk2bf(xr[0]+F.bxv[ti][0], pr[0]+F.bpv[ti][0]),
                              pk2bf(xr[1]+F.bxv[ti][1], pr[1]+F.bpv[ti][1]),
                              pk2bf(xr[2]+F.bxv[ti][2], pr[2]+F.bpv[ti][2]),
                              pk2bf(xr[3]+F.bxv[ti][3], pr[3]+F.bpv[ti][3]));
        uint4 uc = make_uint4(pk2bf(xc[0], pc[0]), pk2bf(xc[1], pc[1]),
                              pk2bf(xc[2], pc[2]), pk2bf(xc[3], pc[3]));
        *(uint4*)(Ar + (size_t)nd*128 + hbase) = ur;
        *(uint4*)(Ac + (size_t)nd*128 + hbase) = uc;
      }
    }
  }
  __syncthreads();   // protect xt for next tile
}

// 1024-entry partial exclusive scan (in-place) + block sum
__device__ __forceinline__ void scan_a_job(
    int job, int* __restrict__ hist, int N, int* __restrict__ bsum,
    int* wtot, int* wexc, int t) {
  int lane = t & 63, w = t >> 6;
  int base = job * 1024 + t * 4;
  int v0 = (base + 0 < N) ? hist[base + 0] : 0;
  int v1 = (base + 1 < N) ? hist[base + 1] : 0;
  int v2 = (base + 2 < N) ? hist[base + 2] : 0;
  int v3 = (base + 3 < N) ? hist[base + 3] : 0;
  int T = v0 + v1 + v2 + v3;
  int inc = T;
  #pragma unroll
  for (int s = 1; s < 64; s <<= 1) {
    int u = __shfl_up(inc, s, 64);
    if (lane >= s) inc += u;
  }
  if (lane == 63) wtot[w] = inc;
  __syncthreads();
  if (t == 0) {
    int a = 0;
    #pragma unroll
    for (int i = 0; i < 4; ++i) { wexc[i] = a; a += wtot[i]; }
    bsum[job] = a;
  }
  __syncthreads();
  int tex = wexc[w] + (inc - T);
  if (base + 0 < N) hist[base + 0] = tex;
  if (base + 1 < N) hist[base + 1] = tex + v0;
  if (base + 2 < N) hist[base + 2] = tex + v0 + v1;
  if (base + 3 < N) hist[base + 3] = tex + v0 + v1 + v2;
}

// ---------------------------------------------------------------------------
// Cooperative fused prep: one dispatch replaces memset+setup+nodeA+scan+scatter
// P0 zeros+repack | P1 histogram+nodeA | P2 partial scans | P3 scatter.
// 1024 blocks x 256 (4 blocks/CU co-resident; ~9.6 KB LDS, VGPR<=128).
// ---------------------------------------------------------------------------
__global__ __launch_bounds__(256, 4) void k_prep(
    float* __restrict__ out, int out_n,
    const int* __restrict__ rowp, const int* __restrict__ colp, int E,
    int* __restrict__ hist, int N, int* __restrict__ bsum, int NB,
    const float* __restrict__ x,
    const float* __restrict__ W1x, const float* __restrict__ W1p,
    const float* __restrict__ W2x,
    const float* __restrict__ b1x, const float* __restrict__ b1p,
    unsigned short* __restrict__ wbuf,
    unsigned int* __restrict__ Ar, unsigned int* __restrict__ Ac,
    int2* __restrict__ sedge)
{
  cg::grid_group grid = cg::this_grid();
  __shared__ __align__(16) unsigned short xt[64][72];
  __shared__ int wtot[4], wexc[4], boff_sh[64];

  const int t = threadIdx.x;
  const int gsz  = gridDim.x * 256;
  const int gtid = blockIdx.x * 256 + t;

  // ---- P0: zero hist, zero out, repack weights ----
  for (int i = gtid; i < N; i += gsz) hist[i] = 0;
  for (int i = gtid * 4; i < out_n; i += gsz * 4) {
    if (i + 4 <= out_n) *(float4*)(out + i) = make_float4(0.f,0.f,0.f,0.f);
    else for (int k = i; k < out_n; ++k) out[k] = 0.f;
  }
  for (int i = gtid; i < 40960; i += gsz) repack_item(i, W1x, W1p, W2x, wbuf);
  grid.sync();

  // ---- P1: histogram (int4) + nodeA tables ----
  for (int i4 = gtid; i4 < (E >> 2); i4 += gsz) {
    int4 c = *(const int4*)(colp + i4*4);
    atomicAdd(&hist[c.x], 1); atomicAdd(&hist[c.y], 1);
    atomicAdd(&hist[c.z], 1); atomicAdd(&hist[c.w], 1);
  }
  for (int k = (E & ~3) + gtid; k < E; k += gsz) atomicAdd(&hist[colp[k]], 1);
  {
    NodeAFrags F;
    nodeA_load_frags(F, wbuf, b1x, b1p, t >> 6, t & 63, (t & 63) >> 4);
    const int njobs = (N + 63) >> 6;
    for (int job = blockIdx.x; job < njobs; job += gridDim.x)
      nodeA_tile(job * 64, x, F, N, Ar, Ac, xt, t);
  }
  grid.sync();

  // ---- P2: partial scans (NB jobs) ----
  for (int job = blockIdx.x; job < NB; job += gridDim.x)
    scan_a_job(job, hist, N, bsum, wtot, wexc, t);
  grid.sync();

  // ---- P3: scatter with per-block inline scan of bsum (NB <= 64) ----
  if (t < 64) {
    int v = (t < NB) ? bsum[t] : 0;
    int inc = v;
    #pragma unroll
    for (int s = 1; s < 64; s <<= 1) {
      int u = __shfl_up(inc, s, 64);
      if (t >= s) inc += u;
    }
    boff_sh[t] = inc - v;
  }
  __syncthreads();
  for (int i = gtid; i < E; i += gsz) {
    int c = colp[i];
    int p = atomicAdd(&hist[c], 1) + boff_sh[c >> 10];
    sedge[p] = make_int2(rowp[i], c);
  }
}

// ---------------------------------------------------------------------------
// Fallback discrete kernels (exact R7 pipeline), used if cooperative launch
// is rejected (e.g. by graph capture).
// ---------------------------------------------------------------------------
__global__ __launch_bounds__(256) void k_setup(
    float* __restrict__ out, int out_n,
    const int* __restrict__ colp, int E, int* __restrict__ hist,
    const float* __restrict__ W1x, const float* __restrict__ W1p,
    const float* __restrict__ W2x, unsigned short* __restrict__ wbuf,
    int b1, int b2)
{
  int blk = blockIdx.x, t = threadIdx.x;
  if (blk < b1) {
    int i = (blk * 256 + t) * 4;
    if (i + 4 <= out_n) *(float4*)(out + i) = make_float4(0.f,0.f,0.f,0.f);
    else for (int k = i; k < out_n; ++k) out[k] = 0.f;
  } else if (blk < b2) {
    int i = ((blk - b1) * 256 + t) * 4;
    if (i + 4 <= E) {
      int4 c = *(const int4*)(colp + i);
      atomicAdd(&hist[c.x], 1); atomicAdd(&hist[c.y], 1);
      atomicAdd(&hist[c.z], 1); atomicAdd(&hist[c.w], 1);
    } else {
      for (int k = i; k < E; ++k) atomicAdd(&hist[colp[k]], 1);
    }
  } else {
    int i = (blk - b2) * 256 + t;
    if (i < 40960) repack_item(i, W1x, W1p, W2x, wbuf);
  }
}

__global__ __launch_bounds__(256) void k_nodeA(
    const float* __restrict__ x, const unsigned short* __restrict__ wbuf,
    const float* __restrict__ b1x, const float* __restrict__ b1p, int N,
    unsigned int* __restrict__ Ar, unsigned int* __restrict__ Ac)
{
  __shared__ __align__(16) unsigned short xt[64][72];
  const int t = threadIdx.x;
  NodeAFrags F;
  nodeA_load_frags(F, wbuf, b1x, b1p, t >> 6, t & 63, (t & 63) >> 4);
  nodeA_tile(blockIdx.x * 64, x, F, N, Ar, Ac, xt, t);
}

__global__ __launch_bounds__(256) void k_scan_a(
    int* __restrict__ hist, int N, int* __restrict__ bsum) {
  __shared__ int wtot[4], wexc[4];
  scan_a_job(blockIdx.x, hist, N, bsum, wtot, wexc, threadIdx.x);
}

__global__ __launch_bounds__(256) void k_scatter(
    const int* __restrict__ row, const int* __restrict__ col, int E,
    int* __restrict__ excl, const int* __restrict__ bsum, int NB,
    int2* __restrict__ sedge) {
  __shared__ int boff_sh[64];
  int t = threadIdx.x;
  if (t < 64) {
    int v = (t < NB) ? bsum[t] : 0;
    int inc = v;
    #pragma unroll
    for (int s = 1; s < 64; s <<= 1) {
      int u = __shfl_up(inc, s, 64);
      if (t >= s) inc += u;
    }
    boff_sh[t] = inc - v;
  }
  __syncthreads();
  int i = blockIdx.x * 256 + t;
  if (i < E) {
    int c = col[i];
    int p = atomicAdd(&excl[c], 1) + boff_sh[c >> 10];
    sedge[p] = make_int2(row[i], c);
  }
}

// ---------------------------------------------------------------------------
// Main kernel — EXACT R7 structure (137 us proven): 64 sorted edges/block,
// 256 threads. Layer 1 = table gathers h = Ar[row]+Ac[col]+dsq*W1[128];
// layer 2 = MFMA K=128 from H_lds; segmented suffix-sum scatter over sorted
// cols; per-edge phi_p dot + segmented scatter.
// ---------------------------------------------------------------------------
__global__ __launch_bounds__(256) void mp_main(
    const float* __restrict__ pos,
    const int2* __restrict__ sedge, int E,
    const unsigned int* __restrict__ Ar, const unsigned int* __restrict__ Ac,
    const float* __restrict__ W1x, const float* __restrict__ W1p,
    const float* __restrict__ b2x, const float* __restrict__ W2p,
    const float* __restrict__ b2p,
    const unsigned short* __restrict__ wbuf,
    float* __restrict__ out_x, float* __restrict__ out_pos)
{
  __shared__ __align__(16) unsigned short H_lds[64][136];  // 17408 B
  __shared__ __align__(16) uint4 edata[64];                // {row, col, dsq, 0}
  __shared__ float rel_lds[64][3];
  __shared__ int   col_sh[64];
  __shared__ float wsum[4][64];

  const int t    = threadIdx.x;
  const int e0   = blockIdx.x * 64;
  const int wv   = t >> 6;
  const int lane = t & 63;
  const int quad = lane >> 4;
  const int lc   = lane & 15;

  if (t < 64) {
    int e = e0 + t;
    int r = 0, c = 0, cs = -1;
    float rp0 = 0.f, rp1 = 0.f, rp2 = 0.f, dsq = 0.f;
    if (e < E) {
      int2 rc = sedge[e]; r = rc.x; c = rc.y;
      cs = c;
      float pr0 = pos[r*3+0], pr1 = pos[r*3+1], pr2 = pos[r*3+2];
      float pc0 = pos[c*3+0], pc1 = pos[c*3+1], pc2 = pos[c*3+2];
      rp0 = pr0 - pc0; rp1 = pr1 - pc1; rp2 = pr2 - pc2;
      dsq = rp0*rp0 + rp1*rp1 + rp2*rp2;
    }
    rel_lds[t][0] = rp0; rel_lds[t][1] = rp1; rel_lds[t][2] = rp2;
    col_sh[t] = cs;
    edata[t] = make_uint4((unsigned)r, (unsigned)c, __float_as_uint(dsq), 0u);
  }

  const short8* __restrict__ w2x_f = (const short8*)(wbuf + 32768);
  short8 a2w[4];
  #pragma unroll
  for (int ks = 0; ks < 4; ++ks) a2w[ks] = w2x_f[(wv*4 + ks)*64 + lane];

  float w1xd[2][4], w1pd[2][4], wp2[2][4], b2xr[4];
  #pragma unroll
  for (int ti = 0; ti < 2; ++ti)
    #pragma unroll
    for (int r = 0; r < 4; ++r) {
      int h = (wv + 4*ti)*16 + quad*4 + r;
      w1xd[ti][r] = W1x[16384 + h];
      w1pd[ti][r] = W1p[16384 + h];
      wp2[ti][r]  = W2p[h];
    }
  #pragma unroll
  for (int r = 0; r < 4; ++r) b2xr[r] = b2x[wv*16 + quad*4 + r];
  const float b2ps = b2p[0];
  __syncthreads();

  #pragma unroll 2
  for (int et = 0; et < 4; ++et) {
    uint4 ed = edata[et*16 + lc];
    const float dsqv = __uint_as_float(ed.z);
    float ps = 0.f;
    #pragma unroll
    for (int ti = 0; ti < 2; ++ti) {
      const int ht = wv + 4*ti;
      const int hb = ht*32 + quad*8;
      uint4 va = *(const uint4*)((const unsigned short*)Ar + (size_t)ed.x*256 + hb);
      uint4 vc = *(const uint4*)((const unsigned short*)Ac + (size_t)ed.y*256 + hb);
      float sx[4];
      #pragma unroll
      for (int j = 0; j < 4; ++j) {
        unsigned a = (&va.x)[j], bb = (&vc.x)[j];
        float hx = __uint_as_float(a << 16) + __uint_as_float(bb << 16)
                 + dsqv * w1xd[ti][j];
        float hp = __uint_as_float(a & 0xffff0000u) + __uint_as_float(bb & 0xffff0000u)
                 + dsqv * w1pd[ti][j];
        sx[j] = silu(hx);
        ps += silu(hp) * wp2[ti][j];
      }
      *(uint2*)&H_lds[et*16 + lc][ht*16 + quad*4] =
          make_uint2(pk2bf(sx[0], sx[1]), pk2bf(sx[2], sx[3]));
    }
    ps += __shfl_xor(ps, 16, 64);
    ps += __shfl_xor(ps, 32, 64);
    if (lane < 16) wsum[wv][et*16 + lane] = ps;
  }
  __syncthreads();

  #pragma unroll 2
  for (int et = 0; et < 4; ++et) {
    floatx4 acc = {0,0,0,0};
    #pragma unroll
    for (int ks = 0; ks < 4; ++ks) {
      short8 b = *(const short8*)&H_lds[et*16 + lc][ks*32 + quad*8];
      acc = __builtin_amdgcn_mfma_f32_16x16x32_bf16(a2w[ks], b, acc, 0, 0, 0);
    }
    int edge = et*16 + lc;
    int myc = col_sh[edge];
    float v0 = acc[0] + b2xr[0], v1 = acc[1] + b2xr[1];
    float v2 = acc[2] + b2xr[2], v3 = acc[3] + b2xr[3];
    #pragma unroll
    for (int s = 1; s < 16; s <<= 1) {
      int   nc = __shfl_down(myc, s, 64);
      float n0 = __shfl_down(v0,  s, 64);
      float n1 = __shfl_down(v1,  s, 64);
      float n2 = __shfl_down(v2,  s, 64);
      float n3 = __shfl_down(v3,  s, 64);
      if ((lc + s < 16) && (nc == myc)) { v0 += n0; v1 += n1; v2 += n2; v3 += n3; }
    }
    bool head = (myc >= 0) && (lc == 0 || col_sh[edge-1] != myc);
    if (head) {
      float* dst = out_x + (size_t)myc*64 + wv*16 + quad*4;
      atomicAdd(dst + 0, v0);
      atomicAdd(dst + 1, v1);
      atomicAdd(dst + 2, v2);
      atomicAdd(dst + 3, v3);
    }
  }

  if (t < 64) {
    int c = col_sh[t];
    float w = wsum[0][t] + wsum[1][t] + wsum[2][t] + wsum[3][t] + b2ps;
    float p0 = w * rel_lds[t][0], p1 = w * rel_lds[t][1], p2 = w * rel_lds[t][2];
    #pragma unroll
    for (int s = 1; s < 64; s <<= 1) {
      int   nc = __shfl_down(c,  s, 64);
      float n0 = __shfl_down(p0, s, 64);
      float n1 = __shfl_down(p1, s, 64);
      float n2 = __shfl_down(p2, s, 64);
      if ((t + s < 64) && (nc == c)) { p0 += n0; p1 += n1; p2 += n2; }
    }
    bool head = (c >= 0) && (t == 0 || col_sh[t-1] != c);
    if (head) {
      atomicAdd(&out_pos[(size_t)c*3 + 0], p0);
      atomicAdd(&out_pos[(size_t)c*3 + 1], p1);
      atomicAdd(&out_pos[(size_t)c*3 + 2], p2);
    }
  }
}

extern "C" void kernel_launch(void* const* d_in, const int* in_sizes, int n_in,
                              void* d_out, int out_size, void* d_ws, size_t ws_size,
                              hipStream_t stream) {
  const float* x   = (const float*)d_in[0];
  const float* pos = (const float*)d_in[1];
  const int*   ei  = (const int*)d_in[2];
  const float* W1x = (const float*)d_in[3];
  const float* b1x = (const float*)d_in[4];
  const float* W2x = (const float*)d_in[5];
  const float* b2x = (const float*)d_in[6];
  const float* W1p = (const float*)d_in[7];
  const float* b1p = (const float*)d_in[8];
  const float* W2p = (const float*)d_in[9];
  const float* b2p = (const float*)d_in[10];

  const int E = in_sizes[2] / 2;        // 800000
  const int N = in_sizes[0] / 64;       // 50000
  const int* rowp = ei;
  const int* colp = ei + E;
  float* out_x   = (float*)d_out;
  float* out_pos = out_x + (size_t)N * 64;
  const int NB = (N + 1023) / 1024;     // 49

  // ws layout: [Ar][Ac][wbuf][hist][bsum][sedge]
  char* ws = (char*)d_ws;
  const size_t tab_one = (size_t)N * 512;
  unsigned int*   Ar   = (unsigned int*)ws;
  unsigned int*   Ac   = (unsigned int*)(ws + tab_one);
  unsigned short* wbuf = (unsigned short*)(ws + 2*tab_one);
  int*  hist  = (int*)(ws + 2*tab_one + 81920);
  int*  bsum  = (int*)(ws + 2*tab_one + 81920 + 200192);
  int2* sedge = (int2*)(ws + 2*tab_one + 81920 + 200192 + 512);

  // ---- try single cooperative prep dispatch ----
  float* outp = (float*)d_out;
  int out_n = out_size, Ev = E, Nv = N, NBv = NB;
  const int *rp = rowp, *cp = colp;
  const float *xp = x, *w1xp = W1x, *w1pp = W1p, *w2xp = W2x, *b1xp = b1x, *b1pp = b1p;
  int *histp = hist, *bsump = bsum;
  unsigned short* wbufp = wbuf;
  unsigned int *Arp = Ar, *Acp = Ac;
  int2* sedgep = sedge;
  void* cargs[] = {&outp, &out_n, &rp, &cp, &Ev, &histp, &Nv, &bsump, &NBv,
                   &xp, &w1xp, &w1pp, &w2xp, &b1xp, &b1pp, &wbufp, &Arp, &Acp,
                   &sedgep};
  hipError_t cerr = hipLaunchCooperativeKernel(
      reinterpret_cast<void*>(k_prep), dim3(1024), dim3(256), cargs, 0, stream);

  if (cerr != hipSuccess) {
    (void)hipGetLastError();   // clear sticky error; run discrete fallback
    hipMemsetAsync(hist, 0, (size_t)N * sizeof(int), stream);
    const int nb_out  = (out_size + 1023) / 1024;
    const int nb_hist = (E/4 + 255) / 256 + 1;
    const int b1 = nb_out, b2 = b1 + nb_hist;
    k_setup<<<b2 + 160, 256, 0, stream>>>((float*)d_out, out_size, colp, E,
                                          hist, W1x, W1p, W2x, wbuf, b1, b2);
    k_nodeA<<<(N + 63) / 64, 256, 0, stream>>>(x, wbuf, b1x, b1p, N, Ar, Ac);
    k_scan_a<<<NB, 256, 0, stream>>>(hist, N, bsum);
    k_scatter<<<(E + 255) / 256, 256, 0, stream>>>(rowp, colp, E, hist, bsum,
                                                   NB, sedge);
  }

  mp_main<<<(E + 63) / 64, 256, 0, stream>>>(
      pos, sedge, E, Ar, Ac, W1x, W1p, b2x, W2p, b2p, wbuf, out_x, out_pos);
}

// Round 10
// 311.866 us; speedup vs baseline: 2.0430x; 2.0430x over previous
//
#include <hip/hip_runtime.h>

typedef short short8 __attribute__((ext_vector_type(8)));
typedef float floatx4 __attribute__((ext_vector_type(4)));

__device__ __forceinline__ unsigned short f2bf(float f) {
  unsigned int u = __float_as_uint(f);
  u += 0x7FFFu + ((u >> 16) & 1u);   // RNE
  return (unsigned short)(u >> 16);
}

#if __has_builtin(__builtin_amdgcn_cvt_pk_bf16_f32)
typedef __bf16 bf16x2_t __attribute__((ext_vector_type(2)));
__device__ __forceinline__ unsigned int pk2bf(float lo, float hi) {
  bf16x2_t v = __builtin_amdgcn_cvt_pk_bf16_f32(lo, hi);
  return __builtin_bit_cast(unsigned int, v);
}
#else
__device__ __forceinline__ unsigned int pk2bf(float lo, float hi) {
  return (unsigned)f2bf(lo) | ((unsigned)f2bf(hi) << 16);
}
#endif

__device__ __forceinline__ float silu(float h) {
  return h * __builtin_amdgcn_rcpf(1.f + __expf(-h));
}

// ---------------------------------------------------------------------------
// Mega-setup (one dispatch, independent jobs by block range):
//   [0,b1)   nodeA: per-node layer-1 tables; W1 fragments converted INLINE
//            from f32 globals (no wbuf dependency -> fusable).
//   [b1,b2)  zero d_out (16 floats/thread)
//   [b2,b3)  col histogram (int4; hist pre-zeroed by hipMemsetAsync)
//   [b3,..)  repack W2x -> bf16 fragments (wbuf, 8192 ushorts)
// Table layout: Ar[n][h] = x[n]·W1[0:64,h] + b1[h]; Ac[n][h] = x[n]·W1[64:128,h]
// packed per h: uint = (x_bf16 | p_bf16<<16). nodeA MFMA orientation:
// A = weight frag A[m=h][k], B = x-tile B[k][node] -> D[h][node]; lane lc =
// node, quad*4+r = h-sub -> one aligned uint4 store per (ti, table).
// ---------------------------------------------------------------------------
__global__ __launch_bounds__(256) void k_mega(
    float* __restrict__ out, int out_n,
    const int* __restrict__ colp, int E, int* __restrict__ hist,
    const float* __restrict__ x, int N,
    const float* __restrict__ W1x, const float* __restrict__ W1p,
    const float* __restrict__ W2x,
    const float* __restrict__ b1x, const float* __restrict__ b1p,
    unsigned short* __restrict__ wbuf,
    unsigned int* __restrict__ Ar, unsigned int* __restrict__ Ac,
    int b1, int b2, int b3)
{
  __shared__ __align__(16) unsigned short xt[64][72];
  const int blk = blockIdx.x, t = threadIdx.x;

  if (blk < b1) {
    // ---------------- job nodeA ----------------
    const int n0 = blk * 64;
    const int wv = t >> 6, lane = t & 63, quad = lane >> 4, lc = lane & 15;

    {  // stage x tile (bf16)
      int nd = t >> 2, p = t & 3;
      int n = n0 + nd;
      uint4 o0, o1;
      if (n < N) {
        const float4* xp = (const float4*)(x + (size_t)n*64 + p*16);
        float4 a = xp[0], b = xp[1], c = xp[2], d = xp[3];
        o0 = make_uint4(pk2bf(a.x,a.y), pk2bf(a.z,a.w), pk2bf(b.x,b.y), pk2bf(b.z,b.w));
        o1 = make_uint4(pk2bf(c.x,c.y), pk2bf(c.z,c.w), pk2bf(d.x,d.y), pk2bf(d.z,d.w));
      } else {
        o0 = o1 = make_uint4(0u,0u,0u,0u);
      }
      *(uint4*)&xt[nd][p*16]     = o0;
      *(uint4*)&xt[nd][p*16 + 8] = o1;
    }

    // inline W1 fragment conversion from f32 (L2-hot; 128 loads x 4 arrays)
    short8 fxr[2][2], fxc[2][2], fpr[2][2], fpc[2][2];
    float bxv[2][4], bpv[2][4];
    #pragma unroll
    for (int ti = 0; ti < 2; ++ti) {
      const int nt = wv + 4*ti;
      const int n  = nt*16 + lc;
      #pragma unroll
      for (int k2 = 0; k2 < 2; ++k2) {
        #pragma unroll
        for (int j = 0; j < 8; ++j) {
          const int kr = k2*32 + quad*8 + j;          // 0..63
          fxr[ti][k2][j] = (short)f2bf(W1x[kr*128 + n]);
          fxc[ti][k2][j] = (short)f2bf(W1x[(64 + kr)*128 + n]);
          fpr[ti][k2][j] = (short)f2bf(W1p[kr*128 + n]);
          fpc[ti][k2][j] = (short)f2bf(W1p[(64 + kr)*128 + n]);
        }
      }
      #pragma unroll
      for (int r = 0; r < 4; ++r) {
        bxv[ti][r] = b1x[nt*16 + quad*4 + r];
        bpv[ti][r] = b1p[nt*16 + quad*4 + r];
      }
    }
    __syncthreads();

    #pragma unroll 1
    for (int mw = 0; mw < 4; ++mw) {
      short8 bb0 = *(const short8*)&xt[mw*16 + lc][quad*8];       // k 0..31
      short8 bb1 = *(const short8*)&xt[mw*16 + lc][32 + quad*8];  // k 32..63
      const int nd = n0 + mw*16 + lc;
      #pragma unroll
      for (int ti = 0; ti < 2; ++ti) {
        floatx4 xr = {0,0,0,0}, xc = {0,0,0,0}, pr = {0,0,0,0}, pc = {0,0,0,0};
        xr = __builtin_amdgcn_mfma_f32_16x16x32_bf16(fxr[ti][0], bb0, xr, 0,0,0);
        xr = __builtin_amdgcn_mfma_f32_16x16x32_bf16(fxr[ti][1], bb1, xr, 0,0,0);
        xc = __builtin_amdgcn_mfma_f32_16x16x32_bf16(fxc[ti][0], bb0, xc, 0,0,0);
        xc = __builtin_amdgcn_mfma_f32_16x16x32_bf16(fxc[ti][1], bb1, xc, 0,0,0);
        pr = __builtin_amdgcn_mfma_f32_16x16x32_bf16(fpr[ti][0], bb0, pr, 0,0,0);
        pr = __builtin_amdgcn_mfma_f32_16x16x32_bf16(fpr[ti][1], bb1, pr, 0,0,0);
        pc = __builtin_amdgcn_mfma_f32_16x16x32_bf16(fpc[ti][0], bb0, pc, 0,0,0);
        pc = __builtin_amdgcn_mfma_f32_16x16x32_bf16(fpc[ti][1], bb1, pc, 0,0,0);
        if (nd < N) {
          const int hbase = (wv + 4*ti)*16 + quad*4;
          uint4 ur = make_uint4(pk2bf(xr[0]+bxv[ti][0], pr[0]+bpv[ti][0]),
                                pk2bf(xr[1]+bxv[ti][1], pr[1]+bpv[ti][1]),
                                pk2bf(xr[2]+bxv[ti][2], pr[2]+bpv[ti][2]),
                                pk2bf(xr[3]+bxv[ti][3], pr[3]+bpv[ti][3]));
          uint4 uc = make_uint4(pk2bf(xc[0], pc[0]), pk2bf(xc[1], pc[1]),
                                pk2bf(xc[2], pc[2]), pk2bf(xc[3], pc[3]));
          *(uint4*)(Ar + (size_t)nd*128 + hbase) = ur;
          *(uint4*)(Ac + (size_t)nd*128 + hbase) = uc;
        }
      }
    }
  } else if (blk < b2) {
    // ---------------- job zero d_out ----------------
    int i = ((blk - b1) * 256 + t) * 16;
    #pragma unroll
    for (int q = 0; q < 4; ++q) {
      int j = i + q*4;
      if (j + 4 <= out_n) *(float4*)(out + j) = make_float4(0.f,0.f,0.f,0.f);
      else for (int k = j; k < out_n; ++k) out[k] = 0.f;
    }
  } else if (blk < b3) {
    // ---------------- job histogram ----------------
    int i4 = (blk - b2) * 256 + t;
    if (i4 < (E >> 2)) {
      int4 c = *(const int4*)(colp + i4*4);
      atomicAdd(&hist[c.x], 1); atomicAdd(&hist[c.y], 1);
      atomicAdd(&hist[c.z], 1); atomicAdd(&hist[c.w], 1);
    }
    if (blk == b2 && t == 0)
      for (int k = E & ~3; k < E; ++k) atomicAdd(&hist[colp[k]], 1);
  } else {
    // ---------------- job repack W2x ----------------
    int i = (blk - b3) * 256 + t;
    if (i < 8192) {
      int jj = i & 7, lane = (i >> 3) & 63, ks = (i >> 9) & 3, nt = (i >> 11) & 3;
      int k = ks*32 + (lane >> 4)*8 + jj;
      wbuf[i] = f2bf(W2x[k*64 + nt*16 + (lane & 15)]);
    }
  }
}

// ---------------------------------------------------------------------------
// Counting-sort scan (49 blocks): per-1024 exclusive scan in-place + bsum.
// ---------------------------------------------------------------------------
__global__ __launch_bounds__(256) void k_scan_a(
    int* __restrict__ hist, int N, int* __restrict__ bsum) {
  __shared__ int wtot[4], wexc[4];
  int t = threadIdx.x, lane = t & 63, w = t >> 6;
  int base = blockIdx.x * 1024 + t * 4;
  int v0 = (base + 0 < N) ? hist[base + 0] : 0;
  int v1 = (base + 1 < N) ? hist[base + 1] : 0;
  int v2 = (base + 2 < N) ? hist[base + 2] : 0;
  int v3 = (base + 3 < N) ? hist[base + 3] : 0;
  int T = v0 + v1 + v2 + v3;
  int inc = T;
  #pragma unroll
  for (int s = 1; s < 64; s <<= 1) {
    int u = __shfl_up(inc, s, 64);
    if (lane >= s) inc += u;
  }
  if (lane == 63) wtot[w] = inc;
  __syncthreads();
  if (t == 0) {
    int a = 0;
    #pragma unroll
    for (int i = 0; i < 4; ++i) { wexc[i] = a; a += wtot[i]; }
    bsum[blockIdx.x] = a;
  }
  __syncthreads();
  int tex = wexc[w] + (inc - T);
  if (base + 0 < N) hist[base + 0] = tex;
  if (base + 1 < N) hist[base + 1] = tex + v0;
  if (base + 2 < N) hist[base + 2] = tex + v0 + v1;
  if (base + 3 < N) hist[base + 3] = tex + v0 + v1 + v2;
}

// ---------------------------------------------------------------------------
// Scatter (4 edges/thread, int4) with inline top-level scan of bsum (NB<=64).
// ---------------------------------------------------------------------------
__global__ __launch_bounds__(256) void k_scatter(
    const int* __restrict__ row, const int* __restrict__ col, int E,
    int* __restrict__ excl, const int* __restrict__ bsum, int NB,
    int2* __restrict__ sedge) {
  __shared__ int boff_sh[64];
  int t = threadIdx.x;
  if (t < 64) {
    int v = (t < NB) ? bsum[t] : 0;
    int inc = v;
    #pragma unroll
    for (int s = 1; s < 64; s <<= 1) {
      int u = __shfl_up(inc, s, 64);
      if (t >= s) inc += u;
    }
    boff_sh[t] = inc - v;
  }
  __syncthreads();
  int i4 = blockIdx.x * 256 + t;
  if (i4 < (E >> 2)) {
    int4 c = *(const int4*)(col + i4*4);
    int4 r = *(const int4*)(row + i4*4);
    int p;
    p = atomicAdd(&excl[c.x], 1) + boff_sh[c.x >> 10]; sedge[p] = make_int2(r.x, c.x);
    p = atomicAdd(&excl[c.y], 1) + boff_sh[c.y >> 10]; sedge[p] = make_int2(r.y, c.y);
    p = atomicAdd(&excl[c.z], 1) + boff_sh[c.z >> 10]; sedge[p] = make_int2(r.z, c.z);
    p = atomicAdd(&excl[c.w], 1) + boff_sh[c.w >> 10]; sedge[p] = make_int2(r.w, c.w);
  }
  if (blockIdx.x == 0 && t == 0) {
    for (int k = E & ~3; k < E; ++k) {
      int c = col[k];
      int p = atomicAdd(&excl[c], 1) + boff_sh[c >> 10];
      sedge[p] = make_int2(row[k], c);
    }
  }
}

// ---------------------------------------------------------------------------
// Main kernel — EXACT R7 structure (137 us proven): 64 sorted edges/block,
// 256 threads. Layer 1 = table gathers h = Ar[row]+Ac[col]+dsq*W1[128];
// layer 2 = MFMA K=128 from H_lds; segmented suffix-sum scatter over sorted
// cols; per-edge phi_p dot + segmented scatter.
// ---------------------------------------------------------------------------
__global__ __launch_bounds__(256) void mp_main(
    const float* __restrict__ pos,
    const int2* __restrict__ sedge, int E,
    const unsigned int* __restrict__ Ar, const unsigned int* __restrict__ Ac,
    const float* __restrict__ W1x, const float* __restrict__ W1p,
    const float* __restrict__ b2x, const float* __restrict__ W2p,
    const float* __restrict__ b2p,
    const unsigned short* __restrict__ wbuf,
    float* __restrict__ out_x, float* __restrict__ out_pos)
{
  __shared__ __align__(16) unsigned short H_lds[64][136];  // 17408 B
  __shared__ __align__(16) uint4 edata[64];                // {row, col, dsq, 0}
  __shared__ float rel_lds[64][3];
  __shared__ int   col_sh[64];
  __shared__ float wsum[4][64];

  const int t    = threadIdx.x;
  const int e0   = blockIdx.x * 64;
  const int wv   = t >> 6;
  const int lane = t & 63;
  const int quad = lane >> 4;
  const int lc   = lane & 15;

  if (t < 64) {
    int e = e0 + t;
    int r = 0, c = 0, cs = -1;
    float rp0 = 0.f, rp1 = 0.f, rp2 = 0.f, dsq = 0.f;
    if (e < E) {
      int2 rc = sedge[e]; r = rc.x; c = rc.y;
      cs = c;
      float pr0 = pos[r*3+0], pr1 = pos[r*3+1], pr2 = pos[r*3+2];
      float pc0 = pos[c*3+0], pc1 = pos[c*3+1], pc2 = pos[c*3+2];
      rp0 = pr0 - pc0; rp1 = pr1 - pc1; rp2 = pr2 - pc2;
      dsq = rp0*rp0 + rp1*rp1 + rp2*rp2;
    }
    rel_lds[t][0] = rp0; rel_lds[t][1] = rp1; rel_lds[t][2] = rp2;
    col_sh[t] = cs;
    edata[t] = make_uint4((unsigned)r, (unsigned)c, __float_as_uint(dsq), 0u);
  }

  const short8* __restrict__ w2x_f = (const short8*)wbuf;
  short8 a2w[4];
  #pragma unroll
  for (int ks = 0; ks < 4; ++ks) a2w[ks] = w2x_f[(wv*4 + ks)*64 + lane];

  float w1xd[2][4], w1pd[2][4], wp2[2][4], b2xr[4];
  #pragma unroll
  for (int ti = 0; ti < 2; ++ti)
    #pragma unroll
    for (int r = 0; r < 4; ++r) {
      int h = (wv + 4*ti)*16 + quad*4 + r;
      w1xd[ti][r] = W1x[16384 + h];     // dist^2 row (row 128 of [129][128])
      w1pd[ti][r] = W1p[16384 + h];
      wp2[ti][r]  = W2p[h];
    }
  #pragma unroll
  for (int r = 0; r < 4; ++r) b2xr[r] = b2x[wv*16 + quad*4 + r];
  const float b2ps = b2p[0];
  __syncthreads();

  #pragma unroll 2
  for (int et = 0; et < 4; ++et) {
    uint4 ed = edata[et*16 + lc];
    const float dsqv = __uint_as_float(ed.z);
    float ps = 0.f;
    #pragma unroll
    for (int ti = 0; ti < 2; ++ti) {
      const int ht = wv + 4*ti;
      const int hb = ht*32 + quad*8;
      uint4 va = *(const uint4*)((const unsigned short*)Ar + (size_t)ed.x*256 + hb);
      uint4 vc = *(const uint4*)((const unsigned short*)Ac + (size_t)ed.y*256 + hb);
      float sx[4];
      #pragma unroll
      for (int j = 0; j < 4; ++j) {
        unsigned a = (&va.x)[j], bb = (&vc.x)[j];
        float hx = __uint_as_float(a << 16) + __uint_as_float(bb << 16)
                 + dsqv * w1xd[ti][j];
        float hp = __uint_as_float(a & 0xffff0000u) + __uint_as_float(bb & 0xffff0000u)
                 + dsqv * w1pd[ti][j];
        sx[j] = silu(hx);
        ps += silu(hp) * wp2[ti][j];
      }
      *(uint2*)&H_lds[et*16 + lc][ht*16 + quad*4] =
          make_uint2(pk2bf(sx[0], sx[1]), pk2bf(sx[2], sx[3]));
    }
    ps += __shfl_xor(ps, 16, 64);
    ps += __shfl_xor(ps, 32, 64);
    if (lane < 16) wsum[wv][et*16 + lane] = ps;
  }
  __syncthreads();

  #pragma unroll 2
  for (int et = 0; et < 4; ++et) {
    floatx4 acc = {0,0,0,0};
    #pragma unroll
    for (int ks = 0; ks < 4; ++ks) {
      short8 b = *(const short8*)&H_lds[et*16 + lc][ks*32 + quad*8];
      acc = __builtin_amdgcn_mfma_f32_16x16x32_bf16(a2w[ks], b, acc, 0, 0, 0);
    }
    int edge = et*16 + lc;
    int myc = col_sh[edge];
    float v0 = acc[0] + b2xr[0], v1 = acc[1] + b2xr[1];
    float v2 = acc[2] + b2xr[2], v3 = acc[3] + b2xr[3];
    #pragma unroll
    for (int s = 1; s < 16; s <<= 1) {
      int   nc = __shfl_down(myc, s, 64);
      float n0 = __shfl_down(v0,  s, 64);
      float n1 = __shfl_down(v1,  s, 64);
      float n2 = __shfl_down(v2,  s, 64);
      float n3 = __shfl_down(v3,  s, 64);
      if ((lc + s < 16) && (nc == myc)) { v0 += n0; v1 += n1; v2 += n2; v3 += n3; }
    }
    bool head = (myc >= 0) && (lc == 0 || col_sh[edge-1] != myc);
    if (head) {
      float* dst = out_x + (size_t)myc*64 + wv*16 + quad*4;
      atomicAdd(dst + 0, v0);
      atomicAdd(dst + 1, v1);
      atomicAdd(dst + 2, v2);
      atomicAdd(dst + 3, v3);
    }
  }

  if (t < 64) {
    int c = col_sh[t];
    float w = wsum[0][t] + wsum[1][t] + wsum[2][t] + wsum[3][t] + b2ps;
    float p0 = w * rel_lds[t][0], p1 = w * rel_lds[t][1], p2 = w * rel_lds[t][2];
    #pragma unroll
    for (int s = 1; s < 64; s <<= 1) {
      int   nc = __shfl_down(c,  s, 64);
      float n0 = __shfl_down(p0, s, 64);
      float n1 = __shfl_down(p1, s, 64);
      float n2 = __shfl_down(p2, s, 64);
      if ((t + s < 64) && (nc == c)) { p0 += n0; p1 += n1; p2 += n2; }
    }
    bool head = (c >= 0) && (t == 0 || col_sh[t-1] != c);
    if (head) {
      atomicAdd(&out_pos[(size_t)c*3 + 0], p0);
      atomicAdd(&out_pos[(size_t)c*3 + 1], p1);
      atomicAdd(&out_pos[(size_t)c*3 + 2], p2);
    }
  }
}

extern "C" void kernel_launch(void* const* d_in, const int* in_sizes, int n_in,
                              void* d_out, int out_size, void* d_ws, size_t ws_size,
                              hipStream_t stream) {
  const float* x   = (const float*)d_in[0];
  const float* pos = (const float*)d_in[1];
  const int*   ei  = (const int*)d_in[2];
  const float* W1x = (const float*)d_in[3];
  const float* b1x = (const float*)d_in[4];
  const float* W2x = (const float*)d_in[5];
  const float* b2x = (const float*)d_in[6];
  const float* W1p = (const float*)d_in[7];
  const float* b1p = (const float*)d_in[8];
  const float* W2p = (const float*)d_in[9];
  const float* b2p = (const float*)d_in[10];

  const int E = in_sizes[2] / 2;        // 800000
  const int N = in_sizes[0] / 64;       // 50000
  const int* rowp = ei;
  const int* colp = ei + E;
  float* out_x   = (float*)d_out;
  float* out_pos = out_x + (size_t)N * 64;
  const int NB = (N + 1023) / 1024;     // 49

  // ws layout: [Ar][Ac][wbuf(W2 frags, 16 KB)][hist][bsum][sedge]
  char* ws = (char*)d_ws;
  const size_t tab_one = (size_t)N * 512;
  unsigned int*   Ar   = (unsigned int*)ws;
  unsigned int*   Ac   = (unsigned int*)(ws + tab_one);
  unsigned short* wbuf = (unsigned short*)(ws + 2*tab_one);
  int*  hist  = (int*)(ws + 2*tab_one + 16384);
  int*  bsum  = (int*)(ws + 2*tab_one + 16384 + 200192);
  int2* sedge = (int2*)(ws + 2*tab_one + 16384 + 200192 + 512);

  hipMemsetAsync(hist, 0, (size_t)N * sizeof(int), stream);

  // mega-setup: nodeA | zero d_out | histogram | repack W2x
  const int nb_node = (N + 63) / 64;                 // 782
  const int nb_zero = (out_size + 4095) / 4096;      // 818
  const int nb_hist = ((E >> 2) + 255) / 256;        // 782
  const int nb_rep  = 32;
  const int b1 = nb_node, b2 = b1 + nb_zero, b3 = b2 + nb_hist;
  k_mega<<<b3 + nb_rep, 256, 0, stream>>>(
      (float*)d_out, out_size, colp, E, hist, x, N,
      W1x, W1p, W2x, b1x, b1p, wbuf, Ar, Ac, b1, b2, b3);

  k_scan_a<<<NB, 256, 0, stream>>>(hist, N, bsum);
  k_scatter<<<((E >> 2) + 255) / 256, 256, 0, stream>>>(
      rowp, colp, E, hist, bsum, NB, sedge);

  mp_main<<<(E + 63) / 64, 256, 0, stream>>>(
      pos, sedge, E, Ar, Ac, W1x, W1p, b2x, W2p, b2p, wbuf, out_x, out_pos);
}